// Round 5
// baseline (48.248 us; speedup 1.0000x reference)
//
#include <hip/hip_runtime.h>

#define B_    2
#define NWQ   75
#define PQ    196
#define D_    64
#define WAY   5
#define SHOT  5
#define SSUP  980                  // support patches per (b, way)
#define SPAD  992                  // padded to 62*16
#define HROWS 496                  // support rows per half-block
#define HTILES 31                  // 16-row tiles per half
#define QI_PER_BLK 3
#define QCHUNKS 25                 // 75/3
#define QROWS 588                  // 3*196 query rows per chunk
#define QTILES_BLK 37              // ceil(588/16)
#define NPC  (B_ * WAY * QCHUNKS)  // 250 (pair, chunk) combos

typedef __attribute__((ext_vector_type(8))) short short8;   // 8 bf16 = 4 VGPR
typedef __attribute__((ext_vector_type(4))) float f32x4;

__device__ __forceinline__ ushort f2bf(float f) {
    uint u = __builtin_bit_cast(uint, f);
    u = (u + 0x7FFFu + ((u >> 16) & 1u)) >> 16;
    return (ushort)u;
}

__device__ __forceinline__ short8 pack8(float4 a, float4 b) {
    short8 o;
    o[0] = (short)f2bf(a.x); o[1] = (short)f2bf(a.y);
    o[2] = (short)f2bf(a.z); o[3] = (short)f2bf(a.w);
    o[4] = (short)f2bf(b.x); o[5] = (short)f2bf(b.y);
    o[6] = (short)f2bf(b.z); o[7] = (short)f2bf(b.w);
    return o;
}

// fp32 -> bf16 support panel, padded to [2*5][992][64], PRE-SWIZZLED on 16B
// units (unit' = u ^ (row&7)) so the main kernel can DMA it linearly into LDS.
__global__ __launch_bounds__(256)
void cvt_s_kernel(const float* __restrict__ in, ushort* __restrict__ out) {
    int i = blockIdx.x * blockDim.x + threadIdx.x;   // one 16B unit (8 bf16)
    const int NU = B_ * WAY * SPAD * 8;              // 79360
    if (i >= NU) return;
    int u  = i & 7;
    int r  = (i >> 3) % SPAD;
    int pr = i / (8 * SPAD);                         // b*WAY + w
    short8 o = {0,0,0,0,0,0,0,0};
    if (r < SSUP) {
        const float* src = in + ((size_t)(pr * SSUP + r) * D_ + u * 8);
        float4 f0 = *(const float4*)src;
        float4 f1 = *(const float4*)(src + 4);
        o = pack8(f0, f1);
    }
    int du = u ^ (r & 7);
    *(short8*)(out + ((size_t)(pr * SPAD + r) * 8 + du) * 8) = o;
}

// Per-wave path: load NT query-tile B-fragments (fp32->bf16 in regs), barrier,
// then 31-tile MFMA + med3 top-3 loop over this block's support half; merge
// across lane groups and store per-row partial top-3 to workspace.
template<int NT>
__device__ __forceinline__ void wave_path(
    const short8* __restrict__ lrow, int u0, int u1, int lg, int lr, int wid,
    int h, const float* __restrict__ Qc, float* __restrict__ partBase) {

    short8 bq[NT][2];
    int rows[NT];
    #pragma unroll
    for (int i = 0; i < NT; ++i) {
        int row = (wid + 16 * i) * 16 + lr;
        rows[i] = row;
        int rc = (row < QROWS) ? row : 0;
        const float* qrow = Qc + (size_t)rc * D_;
        float4 fa = *(const float4*)(qrow + lg * 8);
        float4 fb = *(const float4*)(qrow + lg * 8 + 4);
        float4 fc = *(const float4*)(qrow + 32 + lg * 8);
        float4 fd = *(const float4*)(qrow + 32 + lg * 8 + 4);
        bq[i][0] = pack8(fa, fb);
        bq[i][1] = pack8(fc, fd);
    }

    float t3[NT][3];
    #pragma unroll
    for (int i = 0; i < NT; ++i) {
        t3[i][0] = -__builtin_inff(); t3[i][1] = -__builtin_inff(); t3[i][2] = -__builtin_inff();
    }

    // drain DMA + q loads, then block-wide barrier (all 16 waves reach this)
    asm volatile("s_waitcnt vmcnt(0)" ::: "memory");
    __syncthreads();

    // ---- tiles 0..29: no support-row masking needed ----
    #pragma unroll 2
    for (int st = 0; st < HTILES - 1; ++st) {
        const short8* p = lrow + st * 128;   // 16 rows x 8 units per tile
        short8 A0 = p[u0];
        short8 A1 = p[u1];
        f32x4 c[NT];
        __builtin_amdgcn_s_setprio(1);
        #pragma unroll
        for (int i = 0; i < NT; ++i) {
            f32x4 cc = {0.f, 0.f, 0.f, 0.f};
            cc = __builtin_amdgcn_mfma_f32_16x16x32_bf16(A0, bq[i][0], cc, 0, 0, 0);
            cc = __builtin_amdgcn_mfma_f32_16x16x32_bf16(A1, bq[i][1], cc, 0, 0, 0);
            c[i] = cc;
        }
        __builtin_amdgcn_s_setprio(0);
        #pragma unroll
        for (int i = 0; i < NT; ++i) {
            #pragma unroll
            for (int r = 0; r < 4; ++r) {
                float v = c[i][r];
                t3[i][2] = __builtin_amdgcn_fmed3f(v, t3[i][1], t3[i][2]);
                t3[i][1] = __builtin_amdgcn_fmed3f(v, t3[i][0], t3[i][1]);
                t3[i][0] = fmaxf(v, t3[i][0]);
            }
        }
    }
    // ---- last tile: mask global support rows >= 980 (h=1 pad rows) ----
    {
        const short8* p = lrow + (HTILES - 1) * 128;
        short8 A0 = p[u0];
        short8 A1 = p[u1];
        #pragma unroll
        for (int i = 0; i < NT; ++i) {
            f32x4 cc = {0.f, 0.f, 0.f, 0.f};
            cc = __builtin_amdgcn_mfma_f32_16x16x32_bf16(A0, bq[i][0], cc, 0, 0, 0);
            cc = __builtin_amdgcn_mfma_f32_16x16x32_bf16(A1, bq[i][1], cc, 0, 0, 0);
            #pragma unroll
            for (int r = 0; r < 4; ++r) {
                int srow = h * HROWS + (HTILES - 1) * 16 + lg * 4 + r;
                float v = (srow < SSUP) ? cc[r] : -__builtin_inff();
                t3[i][2] = __builtin_amdgcn_fmed3f(v, t3[i][1], t3[i][2]);
                t3[i][1] = __builtin_amdgcn_fmed3f(v, t3[i][0], t3[i][1]);
                t3[i][0] = fmaxf(v, t3[i][0]);
            }
        }
    }

    // ---- merge top-3 across the 4 lane groups; store partial per q-row ----
    #pragma unroll
    for (int i = 0; i < NT; ++i) {
        float t0 = t3[i][0], t1 = t3[i][1], t2 = t3[i][2];
        #pragma unroll
        for (int m = 16; m <= 32; m <<= 1) {
            float o0 = __shfl_xor(t0, m, 64);
            float o1 = __shfl_xor(t1, m, 64);
            float o2 = __shfl_xor(t2, m, 64);
            t2 = __builtin_amdgcn_fmed3f(o0, t1, t2);
            t1 = __builtin_amdgcn_fmed3f(o0, t0, t1);
            t0 = fmaxf(o0, t0);
            t2 = __builtin_amdgcn_fmed3f(o1, t1, t2);
            t1 = __builtin_amdgcn_fmed3f(o1, t0, t1);
            t0 = fmaxf(o1, t0);
            t2 = __builtin_amdgcn_fmed3f(o2, t1, t2);
            t1 = __builtin_amdgcn_fmed3f(o2, t0, t1);
            t0 = fmaxf(o2, t0);
        }
        if (rows[i] < QROWS && (threadIdx.x & 63) < 16) {
            float* dst = partBase + (size_t)rows[i] * 3;
            dst[0] = t0; dst[1] = t1; dst[2] = t2;
        }
    }
}

// Block = (pc, h): pc = (b*WAY+w)*QCHUNKS + chunk, h = support half.
// Grid is XCD-swizzled so both halves of a pc land on the same XCD.
__global__ __launch_bounds__(1024, 8)
void lpc_half(const float* __restrict__ qf, const ushort* __restrict__ Sb,
              float* __restrict__ part) {
    const int gid = blockIdx.x;             // 0..511
    const int pc  = (gid >> 4) * 8 + (gid & 7);
    const int h   = (gid >> 3) & 1;
    if (pc >= NPC) return;
    const int pair  = pc / QCHUNKS;         // b*WAY + w
    const int chunk = pc % QCHUNKS;
    const int b   = pair / WAY;
    const int qi0 = chunk * QI_PER_BLK;
    const int tid  = threadIdx.x;
    const int wid  = tid >> 6;              // 0..15
    const int lane = tid & 63;
    const int lr   = lane & 15;
    const int lg   = lane >> 4;

    __shared__ short8 ldsv[HROWS * 8];      // 63488 B: 2 blocks/CU fit

    // ---- DMA this half's pre-swizzled panel into LDS (linear copy) ----
    const char* gsrc = (const char*)(Sb + ((size_t)pair * SPAD + (size_t)h * HROWS) * D_);
    char* lbase = (char*)&ldsv[0];
    #pragma unroll
    for (int it = 0; it < 4; ++it) {
        int unit = it * 1024 + tid;         // 16B units, 3968 total
        if (unit < HROWS * 8) {
#if __has_builtin(__builtin_amdgcn_global_load_lds)
            __builtin_amdgcn_global_load_lds(
                (const __attribute__((address_space(1))) unsigned int*)(gsrc + (size_t)unit * 16),
                (__attribute__((address_space(3))) unsigned int*)(lbase + (size_t)unit * 16),
                16, 0, 0);
#else
            *(short8*)(lbase + (size_t)unit * 16) = *(const short8*)(gsrc + (size_t)unit * 16);
#endif
        }
    }

    const float* Qc = qf + (size_t)(b * NWQ + qi0) * PQ * D_;
    float* partBase = part + (size_t)(pc * 2 + h) * QROWS * 3;

    const int u0 = lg ^ (lr & 7);
    const int u1 = (4 + lg) ^ (lr & 7);
    const short8* lrow = ldsv + (lr << 3);

    if (wid < QTILES_BLK - 2 * 16)          // waves 0..4 own a third q-tile
        wave_path<3>(lrow, u0, u1, lg, lr, wid, h, Qc, partBase);
    else
        wave_path<2>(lrow, u0, u1, lg, lr, wid, h, Qc, partBase);
}

// Merge the two halves' per-row top-3, sum per qi, write output.
__global__ __launch_bounds__(256)
void merge_kernel(const float* __restrict__ part, float* __restrict__ out) {
    const int pc  = blockIdx.x;             // 0..249
    const int tid = threadIdx.x;
    __shared__ float sums[QI_PER_BLK];
    if (tid < QI_PER_BLK) sums[tid] = 0.f;
    __syncthreads();

    for (int r = tid; r < QROWS; r += 256) {
        const float* p0 = part + ((size_t)(pc * 2 + 0) * QROWS + r) * 3;
        const float* p1 = part + ((size_t)(pc * 2 + 1) * QROWS + r) * 3;
        float t0 = p0[0], t1 = p0[1], t2 = p0[2];
        #pragma unroll
        for (int j = 0; j < 3; ++j) {
            float v = p1[j];
            t2 = __builtin_amdgcn_fmed3f(v, t1, t2);
            t1 = __builtin_amdgcn_fmed3f(v, t0, t1);
            t0 = fmaxf(v, t0);
        }
        atomicAdd(&sums[r / PQ], t0 + t1 + t2);
    }
    __syncthreads();
    if (tid < QI_PER_BLK) {
        int pair = pc / QCHUNKS, chunk = pc % QCHUNKS;
        int b = pair / WAY, w = pair % WAY;
        out[((size_t)b * NWQ + chunk * QI_PER_BLK + tid) * WAY + w] =
            sums[tid] * (1.0f / (PQ * 3.0f));
    }
}

// ---------------- fp32 fallback if ws too small ----------------
__global__ __launch_bounds__(256)
void lpc_kernel(const float* __restrict__ qfea,
                const float* __restrict__ sfea,
                float* __restrict__ out) {
    const int blk = blockIdx.x;
    const int w  = blk % WAY;
    const int qi = (blk / WAY) % NWQ;
    const int b  = blk / (WAY * NWQ);
    const int p  = threadIdx.x;
    float sum3 = 0.0f;
    if (p < PQ) {
        float qreg[D_];
        const float4* q4 = reinterpret_cast<const float4*>(
            qfea + (((size_t)b * NWQ + qi) * PQ + p) * D_);
        #pragma unroll
        for (int i = 0; i < D_ / 4; ++i) {
            float4 v = q4[i];
            qreg[4*i+0] = v.x; qreg[4*i+1] = v.y; qreg[4*i+2] = v.z; qreg[4*i+3] = v.w;
        }
        const float* sbase = sfea + ((size_t)b * WAY + w) * SSUP * D_;
        float t0 = -INFINITY, t1 = -INFINITY, t2 = -INFINITY;
        for (int s = 0; s < SSUP; ++s) {
            const float4* s4 = reinterpret_cast<const float4*>(sbase + (size_t)s * D_);
            float a0 = 0.f, a1 = 0.f, a2 = 0.f, a3 = 0.f;
            #pragma unroll
            for (int i = 0; i < D_ / 4; ++i) {
                float4 v = s4[i];
                a0 = fmaf(qreg[4*i+0], v.x, a0);
                a1 = fmaf(qreg[4*i+1], v.y, a1);
                a2 = fmaf(qreg[4*i+2], v.z, a2);
                a3 = fmaf(qreg[4*i+3], v.w, a3);
            }
            float dot = (a0 + a1) + (a2 + a3);
            float m0 = fminf(dot, t0);  t0 = fmaxf(dot, t0);
            float m1 = fminf(m0, t1);   t1 = fmaxf(m0, t1);
            t2 = fmaxf(m1, t2);
        }
        sum3 = t0 + t1 + t2;
    }
    __shared__ float red[256];
    red[threadIdx.x] = sum3;
    __syncthreads();
    #pragma unroll
    for (int off = 128; off > 0; off >>= 1) {
        if (threadIdx.x < off) red[threadIdx.x] += red[threadIdx.x + off];
        __syncthreads();
    }
    if (threadIdx.x == 0) out[blk] = red[0] * (1.0f / (PQ * 3.0f));
}

extern "C" void kernel_launch(void* const* d_in, const int* in_sizes, int n_in,
                              void* d_out, int out_size, void* d_ws, size_t ws_size,
                              hipStream_t stream) {
    const float* qf = (const float*)d_in[0];   // [2,75,196,64]
    const float* sf = (const float*)d_in[1];   // [2,5,5,196,64]
    float* out = (float*)d_out;                // [150,5]

    const size_t sBytes = (size_t)B_ * WAY * SPAD * D_ * sizeof(ushort);  // 1,269,760
    const size_t pBytes = (size_t)NPC * 2 * QROWS * 3 * sizeof(float);    // 3,528,000
    const size_t need   = sBytes + pBytes;                                // ~4.8 MB

    if (ws_size >= need) {
        ushort* Sb  = (ushort*)d_ws;
        float* part = (float*)((char*)d_ws + sBytes);   // 16B-aligned
        const int NU = B_ * WAY * SPAD * 8;             // 79360 units
        cvt_s_kernel<<<(NU + 255) / 256, 256, 0, stream>>>(sf, Sb);
        lpc_half<<<512, 1024, 0, stream>>>(qf, Sb, part);
        merge_kernel<<<NPC, 256, 0, stream>>>(part, out);
    } else {
        lpc_kernel<<<B_ * NWQ * WAY, 256, 0, stream>>>(qf, sf, out);
    }
}

// Round 6
// 47.906 us; speedup vs baseline: 1.0071x; 1.0071x over previous
//
#include <hip/hip_runtime.h>

#define B_    2
#define NWQ   75
#define PQ    196
#define D_    64
#define WAY   5
#define SHOT  5
#define SSUP  980                  // support patches per (b, way)
#define SPAD  992                  // padded to 62*16
#define HROWS 496                  // support rows per half-block
#define HTILES 31                  // 16-row tiles per half
#define QI_PER_BLK 3
#define QCHUNKS 25                 // 75/3
#define QROWS 588                  // 3*196 query rows per chunk
#define QTILES_BLK 37              // ceil(588/16)
#define NPC  (B_ * WAY * QCHUNKS)  // 250 (pair, chunk) combos
#define NWAVES 8                   // waves per block (512 threads)

typedef __attribute__((ext_vector_type(8))) short short8;   // 8 bf16 = 4 VGPR
typedef __attribute__((ext_vector_type(4))) float f32x4;

__device__ __forceinline__ ushort f2bf(float f) {
    uint u = __builtin_bit_cast(uint, f);
    u = (u + 0x7FFFu + ((u >> 16) & 1u)) >> 16;
    return (ushort)u;
}

__device__ __forceinline__ short8 pack8(float4 a, float4 b) {
    short8 o;
    o[0] = (short)f2bf(a.x); o[1] = (short)f2bf(a.y);
    o[2] = (short)f2bf(a.z); o[3] = (short)f2bf(a.w);
    o[4] = (short)f2bf(b.x); o[5] = (short)f2bf(b.y);
    o[6] = (short)f2bf(b.z); o[7] = (short)f2bf(b.w);
    return o;
}

// fp32 -> bf16 support panel, padded to [2*5][992][64], PRE-SWIZZLED on 16B
// units (unit' = u ^ (row&7)) so the main kernel can DMA it linearly into LDS.
__global__ __launch_bounds__(256)
void cvt_s_kernel(const float* __restrict__ in, ushort* __restrict__ out) {
    int i = blockIdx.x * blockDim.x + threadIdx.x;   // one 16B unit (8 bf16)
    const int NU = B_ * WAY * SPAD * 8;              // 79360
    if (i >= NU) return;
    int u  = i & 7;
    int r  = (i >> 3) % SPAD;
    int pr = i / (8 * SPAD);                         // b*WAY + w
    short8 o = {0,0,0,0,0,0,0,0};
    if (r < SSUP) {
        const float* src = in + ((size_t)(pr * SSUP + r) * D_ + u * 8);
        float4 f0 = *(const float4*)src;
        float4 f1 = *(const float4*)(src + 4);
        o = pack8(f0, f1);
    }
    int du = u ^ (r & 7);
    *(short8*)(out + ((size_t)(pr * SPAD + r) * 8 + du) * 8) = o;
}

// Per-wave path with NT independent q-tile streams (tile = wid + 8*i).
// High NT amortizes each A-fragment ds_read over NT MFMA pairs and gives the
// scheduler NT independent MFMA->insert chains to overlap.
template<int NT>
__device__ __forceinline__ void wave_path(
    const short8* __restrict__ lrow, int u0, int u1, int lg, int lr, int wid,
    int h, const float* __restrict__ Qc, float* __restrict__ partBase) {

    short8 bq[NT][2];
    int rows[NT];
    #pragma unroll
    for (int i = 0; i < NT; ++i) {
        int row = (wid + NWAVES * i) * 16 + lr;
        rows[i] = row;
        int rc = (row < QROWS) ? row : 0;
        const float* qrow = Qc + (size_t)rc * D_;
        float4 fa = *(const float4*)(qrow + lg * 8);
        float4 fb = *(const float4*)(qrow + lg * 8 + 4);
        float4 fc = *(const float4*)(qrow + 32 + lg * 8);
        float4 fd = *(const float4*)(qrow + 32 + lg * 8 + 4);
        bq[i][0] = pack8(fa, fb);
        bq[i][1] = pack8(fc, fd);
    }

    float t3[NT][3];
    #pragma unroll
    for (int i = 0; i < NT; ++i) {
        t3[i][0] = -__builtin_inff(); t3[i][1] = -__builtin_inff(); t3[i][2] = -__builtin_inff();
    }

    // drain DMA + q loads, then block-wide barrier
    asm volatile("s_waitcnt vmcnt(0)" ::: "memory");
    __syncthreads();

    // ---- tiles 0..29: no support-row masking needed ----
    for (int st = 0; st < HTILES - 1; ++st) {
        const short8* p = lrow + st * 128;   // 16 rows x 8 units per tile
        short8 A0 = p[u0];
        short8 A1 = p[u1];
        f32x4 c[NT];
        __builtin_amdgcn_s_setprio(1);
        #pragma unroll
        for (int i = 0; i < NT; ++i) {
            f32x4 cc = {0.f, 0.f, 0.f, 0.f};
            cc = __builtin_amdgcn_mfma_f32_16x16x32_bf16(A0, bq[i][0], cc, 0, 0, 0);
            cc = __builtin_amdgcn_mfma_f32_16x16x32_bf16(A1, bq[i][1], cc, 0, 0, 0);
            c[i] = cc;
        }
        __builtin_amdgcn_s_setprio(0);
        #pragma unroll
        for (int i = 0; i < NT; ++i) {
            #pragma unroll
            for (int r = 0; r < 4; ++r) {
                float v = c[i][r];
                t3[i][2] = __builtin_amdgcn_fmed3f(v, t3[i][1], t3[i][2]);
                t3[i][1] = __builtin_amdgcn_fmed3f(v, t3[i][0], t3[i][1]);
                t3[i][0] = fmaxf(v, t3[i][0]);
            }
        }
    }
    // ---- last tile: mask global support rows >= 980 (h=1 pad rows) ----
    {
        const short8* p = lrow + (HTILES - 1) * 128;
        short8 A0 = p[u0];
        short8 A1 = p[u1];
        #pragma unroll
        for (int i = 0; i < NT; ++i) {
            f32x4 cc = {0.f, 0.f, 0.f, 0.f};
            cc = __builtin_amdgcn_mfma_f32_16x16x32_bf16(A0, bq[i][0], cc, 0, 0, 0);
            cc = __builtin_amdgcn_mfma_f32_16x16x32_bf16(A1, bq[i][1], cc, 0, 0, 0);
            #pragma unroll
            for (int r = 0; r < 4; ++r) {
                int srow = h * HROWS + (HTILES - 1) * 16 + lg * 4 + r;
                float v = (srow < SSUP) ? cc[r] : -__builtin_inff();
                t3[i][2] = __builtin_amdgcn_fmed3f(v, t3[i][1], t3[i][2]);
                t3[i][1] = __builtin_amdgcn_fmed3f(v, t3[i][0], t3[i][1]);
                t3[i][0] = fmaxf(v, t3[i][0]);
            }
        }
    }

    // ---- merge top-3 across the 4 lane groups; store partial per q-row ----
    #pragma unroll
    for (int i = 0; i < NT; ++i) {
        float t0 = t3[i][0], t1 = t3[i][1], t2 = t3[i][2];
        #pragma unroll
        for (int m = 16; m <= 32; m <<= 1) {
            float o0 = __shfl_xor(t0, m, 64);
            float o1 = __shfl_xor(t1, m, 64);
            float o2 = __shfl_xor(t2, m, 64);
            t2 = __builtin_amdgcn_fmed3f(o0, t1, t2);
            t1 = __builtin_amdgcn_fmed3f(o0, t0, t1);
            t0 = fmaxf(o0, t0);
            t2 = __builtin_amdgcn_fmed3f(o1, t1, t2);
            t1 = __builtin_amdgcn_fmed3f(o1, t0, t1);
            t0 = fmaxf(o1, t0);
            t2 = __builtin_amdgcn_fmed3f(o2, t1, t2);
            t1 = __builtin_amdgcn_fmed3f(o2, t0, t1);
            t0 = fmaxf(o2, t0);
        }
        if (rows[i] < QROWS && (threadIdx.x & 63) < 16) {
            float* dst = partBase + (size_t)rows[i] * 3;
            dst[0] = t0; dst[1] = t1; dst[2] = t2;
        }
    }
}

// Block = (pc, h): pc = (b*WAY+w)*QCHUNKS + chunk, h = support half.
// 512 threads (8 waves), 62KB LDS -> 2 blocks/CU co-resident; VGPR capped 128.
__global__ __launch_bounds__(512, 4)
void lpc_half(const float* __restrict__ qf, const ushort* __restrict__ Sb,
              float* __restrict__ part) {
    const int gid = blockIdx.x;             // 0..511
    const int pc  = (gid >> 4) * 8 + (gid & 7);
    const int h   = (gid >> 3) & 1;
    if (pc >= NPC) return;
    const int pair  = pc / QCHUNKS;         // b*WAY + w
    const int chunk = pc % QCHUNKS;
    const int b   = pair / WAY;
    const int qi0 = chunk * QI_PER_BLK;
    const int tid  = threadIdx.x;
    const int wid  = tid >> 6;              // 0..7
    const int lane = tid & 63;
    const int lr   = lane & 15;
    const int lg   = lane >> 4;

    __shared__ short8 ldsv[HROWS * 8];      // 63488 B

    // ---- DMA this half's pre-swizzled panel into LDS (linear copy) ----
    const char* gsrc = (const char*)(Sb + ((size_t)pair * SPAD + (size_t)h * HROWS) * D_);
    char* lbase = (char*)&ldsv[0];
    #pragma unroll
    for (int it = 0; it < 8; ++it) {
        int unit = it * 512 + tid;          // 16B units, 3968 total
        if (unit < HROWS * 8) {
#if __has_builtin(__builtin_amdgcn_global_load_lds)
            __builtin_amdgcn_global_load_lds(
                (const __attribute__((address_space(1))) unsigned int*)(gsrc + (size_t)unit * 16),
                (__attribute__((address_space(3))) unsigned int*)(lbase + (size_t)unit * 16),
                16, 0, 0);
#else
            *(short8*)(lbase + (size_t)unit * 16) = *(const short8*)(gsrc + (size_t)unit * 16);
#endif
        }
    }

    const float* Qc = qf + (size_t)(b * NWQ + qi0) * PQ * D_;
    float* partBase = part + (size_t)(pc * 2 + h) * QROWS * 3;

    const int u0 = lg ^ (lr & 7);
    const int u1 = (4 + lg) ^ (lr & 7);
    const short8* lrow = ldsv + (lr << 3);

    // 37 q-tiles over 8 waves: waves 0..4 own 5 tiles, waves 5..7 own 4.
    if (wid < QTILES_BLK - 4 * NWAVES)      // wid < 5
        wave_path<5>(lrow, u0, u1, lg, lr, wid, h, Qc, partBase);
    else
        wave_path<4>(lrow, u0, u1, lg, lr, wid, h, Qc, partBase);
}

// Merge the two halves' per-row top-3, sum per qi, write output.
__global__ __launch_bounds__(256)
void merge_kernel(const float* __restrict__ part, float* __restrict__ out) {
    const int pc  = blockIdx.x;             // 0..249
    const int tid = threadIdx.x;
    __shared__ float sums[QI_PER_BLK];
    if (tid < QI_PER_BLK) sums[tid] = 0.f;
    __syncthreads();

    for (int r = tid; r < QROWS; r += 256) {
        const float* p0 = part + ((size_t)(pc * 2 + 0) * QROWS + r) * 3;
        const float* p1 = part + ((size_t)(pc * 2 + 1) * QROWS + r) * 3;
        float t0 = p0[0], t1 = p0[1], t2 = p0[2];
        #pragma unroll
        for (int j = 0; j < 3; ++j) {
            float v = p1[j];
            t2 = __builtin_amdgcn_fmed3f(v, t1, t2);
            t1 = __builtin_amdgcn_fmed3f(v, t0, t1);
            t0 = fmaxf(v, t0);
        }
        atomicAdd(&sums[r / PQ], t0 + t1 + t2);
    }
    __syncthreads();
    if (tid < QI_PER_BLK) {
        int pair = pc / QCHUNKS, chunk = pc % QCHUNKS;
        int b = pair / WAY, w = pair % WAY;
        out[((size_t)b * NWQ + chunk * QI_PER_BLK + tid) * WAY + w] =
            sums[tid] * (1.0f / (PQ * 3.0f));
    }
}

// ---------------- fp32 fallback if ws too small ----------------
__global__ __launch_bounds__(256)
void lpc_kernel(const float* __restrict__ qfea,
                const float* __restrict__ sfea,
                float* __restrict__ out) {
    const int blk = blockIdx.x;
    const int w  = blk % WAY;
    const int qi = (blk / WAY) % NWQ;
    const int b  = blk / (WAY * NWQ);
    const int p  = threadIdx.x;
    float sum3 = 0.0f;
    if (p < PQ) {
        float qreg[D_];
        const float4* q4 = reinterpret_cast<const float4*>(
            qfea + (((size_t)b * NWQ + qi) * PQ + p) * D_);
        #pragma unroll
        for (int i = 0; i < D_ / 4; ++i) {
            float4 v = q4[i];
            qreg[4*i+0] = v.x; qreg[4*i+1] = v.y; qreg[4*i+2] = v.z; qreg[4*i+3] = v.w;
        }
        const float* sbase = sfea + ((size_t)b * WAY + w) * SSUP * D_;
        float t0 = -INFINITY, t1 = -INFINITY, t2 = -INFINITY;
        for (int s = 0; s < SSUP; ++s) {
            const float4* s4 = reinterpret_cast<const float4*>(sbase + (size_t)s * D_);
            float a0 = 0.f, a1 = 0.f, a2 = 0.f, a3 = 0.f;
            #pragma unroll
            for (int i = 0; i < D_ / 4; ++i) {
                float4 v = s4[i];
                a0 = fmaf(qreg[4*i+0], v.x, a0);
                a1 = fmaf(qreg[4*i+1], v.y, a1);
                a2 = fmaf(qreg[4*i+2], v.z, a2);
                a3 = fmaf(qreg[4*i+3], v.w, a3);
            }
            float dot = (a0 + a1) + (a2 + a3);
            float m0 = fminf(dot, t0);  t0 = fmaxf(dot, t0);
            float m1 = fminf(m0, t1);   t1 = fmaxf(m0, t1);
            t2 = fmaxf(m1, t2);
        }
        sum3 = t0 + t1 + t2;
    }
    __shared__ float red[256];
    red[threadIdx.x] = sum3;
    __syncthreads();
    #pragma unroll
    for (int off = 128; off > 0; off >>= 1) {
        if (threadIdx.x < off) red[threadIdx.x] += red[threadIdx.x + off];
        __syncthreads();
    }
    if (threadIdx.x == 0) out[blk] = red[0] * (1.0f / (PQ * 3.0f));
}

extern "C" void kernel_launch(void* const* d_in, const int* in_sizes, int n_in,
                              void* d_out, int out_size, void* d_ws, size_t ws_size,
                              hipStream_t stream) {
    const float* qf = (const float*)d_in[0];   // [2,75,196,64]
    const float* sf = (const float*)d_in[1];   // [2,5,5,196,64]
    float* out = (float*)d_out;                // [150,5]

    const size_t sBytes = (size_t)B_ * WAY * SPAD * D_ * sizeof(ushort);  // 1,269,760
    const size_t pBytes = (size_t)NPC * 2 * QROWS * 3 * sizeof(float);    // 3,528,000
    const size_t need   = sBytes + pBytes;                                // ~4.8 MB

    if (ws_size >= need) {
        ushort* Sb  = (ushort*)d_ws;
        float* part = (float*)((char*)d_ws + sBytes);   // 16B-aligned
        const int NU = B_ * WAY * SPAD * 8;             // 79360 units
        cvt_s_kernel<<<(NU + 255) / 256, 256, 0, stream>>>(sf, Sb);
        lpc_half<<<512, 512, 0, stream>>>(qf, Sb, part);
        merge_kernel<<<NPC, 256, 0, stream>>>(part, out);
    } else {
        lpc_kernel<<<B_ * NWQ * WAY, 256, 0, stream>>>(qf, sf, out);
    }
}